// Round 18
// baseline (347.271 us; speedup 1.0000x reference)
//
#include <hip/hip_runtime.h>
#include <hip/hip_bf16.h>
#include <stdint.h>

// MultiHeadSelfAttention: B=2,H=16,S=2048,D=1024,DK=64. fp32 interface, bf16 MFMA internals.
// d_out = out[2,2048,1024] fp32 ++ attn[2,16,2048,2048] fp32.
//
// R18: SINGLE-PASS attn. Block = 16 q-rows x full 2048 k. Phase A: each of 4 waves
// computes its 512-k slice of exp(S) ONCE into a 64KB LDS row-cache + row-sums.
// Phase B: normalized full-row streaming stores (8KB contiguous per row) + PV from
// LDS-P (unnormalized; O scaled by 1/l at end). Kills the double-QK^T (40% of the
// compute floor) and gives HBM-optimal sequential write streams. 2 barriers total.

typedef __attribute__((ext_vector_type(4))) float f32x4;
typedef __attribute__((ext_vector_type(8))) short s16x8;
typedef __attribute__((ext_vector_type(4))) unsigned int u32x4;
typedef __attribute__((ext_vector_type(4))) unsigned short u16x4;

#define MFMA(a, b, c) __builtin_amdgcn_mfma_f32_16x16x32_bf16((a), (b), (c), 0, 0, 0)

#if __has_builtin(__builtin_amdgcn_exp2f)
#define EXP2(x) __builtin_amdgcn_exp2f(x)
#else
#define EXP2(x) exp2f(x)
#endif

__device__ __forceinline__ unsigned short f2bf(float f) {
    unsigned int u = __float_as_uint(f);
    unsigned int r = (u + 0x7FFFu + ((u >> 16) & 1u)) >> 16;
    return (unsigned short)r;
}
__device__ __forceinline__ float bf2f(unsigned short v) {
    return __uint_as_float(((unsigned int)v) << 16);
}
__device__ __forceinline__ unsigned int cvtpk_bf16(float lo, float hi) {
    unsigned int r;
    asm("v_cvt_pk_bf16_f32 %0, %1, %2" : "=v"(r) : "v"(lo), "v"(hi));
    return r;
}

// ---------------- Kernel 1: fp32 -> bf16 convert (x, wq, wk, wv, wo) ----------------
__global__ void convert_kernel(const float* __restrict__ x,
                               const float* __restrict__ wq, const float* __restrict__ wk,
                               const float* __restrict__ wv, const float* __restrict__ wo,
                               unsigned short* __restrict__ xb, unsigned short* __restrict__ wb) {
    size_t g = (size_t)blockIdx.x * blockDim.x + threadIdx.x;
    size_t i4 = g * 4;
    const float* src;
    unsigned short* dst;
    size_t off;
    if (i4 < 4194304) {            // x: 4096*1024
        src = x; dst = xb; off = i4;
    } else {
        size_t j = i4 - 4194304;
        int wsel = (int)(j >> 20); // each weight 1024*1024
        off = j & 1048575;
        src = (wsel == 0) ? wq : (wsel == 1) ? wk : (wsel == 2) ? wv : wo;
        dst = wb + ((size_t)wsel << 20);
    }
    float4 v = *(const float4*)(src + off);
    u16x4 o;
    o[0] = f2bf(v.x); o[1] = f2bf(v.y); o[2] = f2bf(v.z); o[3] = f2bf(v.w);
    *(u16x4*)(dst + off) = o;
}

// ---------------- Kernel 2/4: bt-GEMM, m97 structure ----------------
// mode 0 epilogue: Qs (scaled), Kb ([bh][s][64]), Vt ([bh][d][s], NO permutation).
__global__ __launch_bounds__(256, 3) void gemm_kernel(
    const unsigned short* __restrict__ A, const unsigned short* __restrict__ B,
    const float* __restrict__ bias_q, const float* __restrict__ bias_k,
    const float* __restrict__ bias_v, int mode,
    unsigned short* __restrict__ Qs, unsigned short* __restrict__ Kb,
    unsigned short* __restrict__ Vt, float* __restrict__ outp) {
    const int t = threadIdx.x;
    const int lane = t & 63;
    const int wv4 = t >> 6;            // wave 0..3
    const int wr = wv4 >> 1, wc = wv4 & 1;
    const int rowbase = blockIdx.y * 128;
    const int colbase = blockIdx.x * 128;

    __shared__ __align__(16) unsigned short lA[128 * 64];
    __shared__ __align__(16) unsigned short lB[128 * 64];

    const int crow = lane >> 3;        // 0..7
    const int ccol = (lane & 7) * 8;   // 0..56

    f32x4 acc[4][4];
#pragma unroll
    for (int mi = 0; mi < 4; ++mi)
#pragma unroll
        for (int ni = 0; ni < 4; ++ni)
            acc[mi][ni] = (f32x4){0.f, 0.f, 0.f, 0.f};

    const int l15 = lane & 15;
    const int koff = (lane >> 4) * 8;
    const int ar = wr * 64 + l15;
    const int br = wc * 64 + l15;

    for (int kt = 0; kt < 16; ++kt) {
        const int kbase = kt * 64 + ccol;
#pragma unroll
        for (int i = 0; i < 4; ++i) {
            const int c = wv4 * 4 + i;
            const int r = c * 8 + crow;
            __builtin_amdgcn_global_load_lds(
                (const __attribute__((address_space(1))) void*)(A + (size_t)(rowbase + r) * 1024 + kbase),
                (__attribute__((address_space(3))) void*)&lA[c * 512], 16, 0, 0);
            __builtin_amdgcn_global_load_lds(
                (const __attribute__((address_space(1))) void*)(B + (size_t)(colbase + r) * 1024 + kbase),
                (__attribute__((address_space(3))) void*)&lB[c * 512], 16, 0, 0);
        }
        __syncthreads();
#pragma unroll
        for (int kk = 0; kk < 2; ++kk) {
            s16x8 af[4], bf[4];
#pragma unroll
            for (int mi = 0; mi < 4; ++mi)
                af[mi] = *(const s16x8*)&lA[(ar + mi * 16) * 64 + kk * 32 + koff];
#pragma unroll
            for (int ni = 0; ni < 4; ++ni)
                bf[ni] = *(const s16x8*)&lB[(br + ni * 16) * 64 + kk * 32 + koff];
#pragma unroll
            for (int mi = 0; mi < 4; ++mi)
#pragma unroll
                for (int ni = 0; ni < 4; ++ni)
                    acc[mi][ni] = MFMA(af[mi], bf[ni], acc[mi][ni]);
        }
        __syncthreads();
    }

    if (mode == 1) {
#pragma unroll
        for (int ni = 0; ni < 4; ++ni) {
            int n = colbase + wc * 64 + ni * 16 + l15;
            float bv = bias_q[n];
#pragma unroll
            for (int mi = 0; mi < 4; ++mi) {
#pragma unroll
                for (int reg = 0; reg < 4; ++reg) {
                    int m = rowbase + wr * 64 + mi * 16 + (lane >> 4) * 4 + reg;
                    outp[(size_t)m * 1024 + n] = acc[mi][ni][reg] + bv;
                }
            }
        }
    } else {
        const int proj = colbase >> 10;
        const float* bias = (proj == 0) ? bias_q : (proj == 1) ? bias_k : bias_v;
        const float scale = (proj == 0) ? 0.18033688011112042f : 1.0f;  // 0.125*log2(e)
#pragma unroll
        for (int ni = 0; ni < 4; ++ni) {
            int n = colbase + wc * 64 + ni * 16 + l15;
            int nn = n & 1023;
            int h = nn >> 6, d = nn & 63;
            float bv = bias[nn];
#pragma unroll
            for (int mi = 0; mi < 4; ++mi) {
                int m0 = rowbase + wr * 64 + mi * 16 + (lane >> 4) * 4;
                int b = m0 >> 11, s0 = m0 & 2047;
                if (proj == 2) {
                    u16x4 pk;
#pragma unroll
                    for (int reg = 0; reg < 4; ++reg)
                        pk[reg] = f2bf(acc[mi][ni][reg] + bv);
                    *(u16x4*)&Vt[((size_t)(b * 16 + h) * 64 + d) * 2048 + s0] = pk;
                } else {
                    unsigned short* dstp = (proj == 0) ? Qs : Kb;
#pragma unroll
                    for (int reg = 0; reg < 4; ++reg)
                        dstp[((size_t)(b * 16 + h) * 2048 + (s0 + reg)) * 64 + d] =
                            f2bf((acc[mi][ni][reg] + bv) * scale);
                }
            }
        }
    }
}

// ---------------- Kernel 3: attention -- single pass, LDS P row-cache ----------------
// Block: 16 q-rows x full 2048 k. 4 waves, wave w owns k-slice [512w, 512w+512).
// Phase A: QK -> exp(S) bf16 -> P_lds + register row-sums. Barrier.
// Phase B: normalized 8KB-row streaming stores (4 rows/wave) + PV from P_lds.
__global__ __launch_bounds__(256, 2) void attn_kernel(
    const unsigned short* __restrict__ Qs, const unsigned short* __restrict__ Kb,
    const unsigned short* __restrict__ Vt, float* __restrict__ attn,
    unsigned short* __restrict__ ctx) {
    const int t = threadIdx.x;
    const int lane = t & 63;
    const int l15 = lane & 15;
    const int g = lane >> 4;
    const int g4 = g * 4, g8 = g * 8;
    const int w = t >> 6;

    // XCD swizzle: 4096 blocks; XCD x owns wid [512x,512x+512) -> bh in {4x..4x+3}
    const int wid = (blockIdx.x & 7) * 512 + (blockIdx.x >> 3);
    const int bh = wid >> 7;      // 0..31
    const int qt16 = wid & 127;   // 0..127 (16-row tiles)
    const int b = bh >> 4, h = bh & 15;

    const unsigned short* Qh = Qs + (size_t)bh * (2048 * 64);
    const unsigned short* Kh = Kb + (size_t)bh * (2048 * 64);
    const unsigned short* Vh = Vt + (size_t)bh * (64 * 2048);
    float* attn_h = attn + (size_t)bh * (2048 * 2048) + (size_t)(qt16 * 16) * 2048;

    __shared__ unsigned short P_lds[16 * 2056];  // 65.8 KB, pitch 2056 (bank spread)
    __shared__ float qpart[4][16];
    __shared__ float rl_lds[16];
    __shared__ float lO[3][16 * 68];             // 13.1 KB partial-O exchange

    // Q fragments (B-operand: q = l15), hoisted
    s16x8 qf[2];
#pragma unroll
    for (int kk = 0; kk < 2; ++kk)
        qf[kk] = *(const s16x8*)&Qh[(size_t)(qt16 * 16 + l15) * 64 + kk * 32 + g8];

    // ---- PHASE A: QK -> exp -> P_lds (own 8 kts) + row-sum partials ----
    float qsum = 0.f;
    for (int i = 0; i < 8; ++i) {
        const int kt = w * 8 + i;
        s16x8 kf[8];
#pragma unroll
        for (int ni = 0; ni < 4; ++ni)
#pragma unroll
            for (int kk = 0; kk < 2; ++kk)
                kf[ni * 2 + kk] =
                    *(const s16x8*)&Kh[(size_t)(kt * 64 + ni * 16 + l15) * 64 + kk * 32 + g8];
        f32x4 sacc[4];
#pragma unroll
        for (int ni = 0; ni < 4; ++ni) sacc[ni] = (f32x4){0.f, 0.f, 0.f, 0.f};
#pragma unroll
        for (int kk = 0; kk < 2; ++kk)
#pragma unroll
            for (int ni = 0; ni < 4; ++ni)
                sacc[ni] = MFMA(kf[ni * 2 + kk], qf[kk], sacc[ni]);
        // S^T frag: col=q=l15, row k = kt*64 + ni*16 + g4 + r. Store exp bf16.
#pragma unroll
        for (int ni = 0; ni < 4; ++ni) {
            float e0 = EXP2(sacc[ni][0]);
            float e1 = EXP2(sacc[ni][1]);
            float e2 = EXP2(sacc[ni][2]);
            float e3 = EXP2(sacc[ni][3]);
            qsum += (e0 + e1) + (e2 + e3);
            u16x4 pk;
            pk[0] = f2bf(e0); pk[1] = f2bf(e1); pk[2] = f2bf(e2); pk[3] = f2bf(e3);
            *(u16x4*)&P_lds[l15 * 2056 + kt * 64 + ni * 16 + g4] = pk;
        }
    }
    // sum over the 4 g-groups (same q=l15)
    qsum += __shfl_xor(qsum, 16);
    qsum += __shfl_xor(qsum, 32);
    if (lane < 16) qpart[w][lane] = qsum;
    __syncthreads();  // barrier 1: P_lds + qpart complete

    if (w == 0 && lane < 16)
        rl_lds[lane] = 1.0f / (qpart[0][lane] + qpart[1][lane] + qpart[2][lane] + qpart[3][lane]);

    // ---- PHASE B1: normalized streaming stores, 4 full rows per wave ----
#pragma unroll
    for (int r = 0; r < 4; ++r) {
        const int row = w * 4 + r;
        const float rlr =
            1.0f / (qpart[0][row] + qpart[1][row] + qpart[2][row] + qpart[3][row]);
#pragma unroll
        for (int sgm = 0; sgm < 8; ++sgm) {
            const int col = sgm * 256 + lane * 4;
            u16x4 pb = *(const u16x4*)&P_lds[row * 2056 + col];
            f32x4 o;
            o[0] = bf2f(pb[0]) * rlr;
            o[1] = bf2f(pb[1]) * rlr;
            o[2] = bf2f(pb[2]) * rlr;
            o[3] = bf2f(pb[3]) * rlr;
            *(f32x4*)&attn_h[(size_t)row * 2048 + col] = o;  // 1KB/instr, 8KB seq/row
        }
    }

    // ---- PHASE B2: PV from P_lds (own 8 kts), unnormalized; scale at end ----
    f32x4 oacc[4];
#pragma unroll
    for (int db = 0; db < 4; ++db) oacc[db] = (f32x4){0.f, 0.f, 0.f, 0.f};
    for (int i = 0; i < 8; ++i) {
        const int kt = w * 8 + i;
        s16x8 pf[2];
#pragma unroll
        for (int ks = 0; ks < 2; ++ks)
            pf[ks] = *(const s16x8*)&P_lds[l15 * 2056 + kt * 64 + ks * 32 + g8];
        s16x8 vf[8];
#pragma unroll
        for (int db = 0; db < 4; ++db)
#pragma unroll
            for (int ks = 0; ks < 2; ++ks)
                vf[db * 2 + ks] =
                    *(const s16x8*)&Vh[(size_t)(db * 16 + l15) * 2048 + kt * 64 + ks * 32 + g8];
#pragma unroll
        for (int db = 0; db < 4; ++db) {
            oacc[db] = MFMA(pf[0], vf[db * 2 + 0], oacc[db]);
            oacc[db] = MFMA(pf[1], vf[db * 2 + 1], oacc[db]);
        }
    }

    // ---- O exchange + ctx write ----
    if (w > 0) {
#pragma unroll
        for (int db = 0; db < 4; ++db)
#pragma unroll
            for (int r = 0; r < 4; ++r)
                lO[w - 1][(g4 + r) * 68 + db * 16 + l15] = oacc[db][r];
    }
    __syncthreads();  // barrier 2
    if (w == 0) {
#pragma unroll
        for (int db = 0; db < 4; ++db) {
#pragma unroll
            for (int r = 0; r < 4; ++r) {
                float s = oacc[db][r] + lO[0][(g4 + r) * 68 + db * 16 + l15] +
                          lO[1][(g4 + r) * 68 + db * 16 + l15] +
                          lO[2][(g4 + r) * 68 + db * 16 + l15];
                s *= rl_lds[g4 + r];
                int q = qt16 * 16 + g4 + r;
                ctx[((size_t)(b * 2048 + q)) * 1024 + h * 64 + db * 16 + l15] = f2bf(s);
            }
        }
    }
}

// ---------------- launcher ----------------
extern "C" void kernel_launch(void* const* d_in, const int* in_sizes, int n_in,
                              void* d_out, int out_size, void* d_ws, size_t ws_size,
                              hipStream_t stream) {
    const float* x  = (const float*)d_in[0];
    const float* wq = (const float*)d_in[1];
    const float* bq = (const float*)d_in[2];
    const float* wk = (const float*)d_in[3];
    const float* bk = (const float*)d_in[4];
    const float* wv = (const float*)d_in[5];
    const float* bv = (const float*)d_in[6];
    const float* wo = (const float*)d_in[7];
    const float* bo = (const float*)d_in[8];

    char* ws = (char*)d_ws;
    unsigned short* xb  = (unsigned short*)(ws);                    // [4096][1024] bf16
    unsigned short* wb  = (unsigned short*)(ws + 8388608);          // [4][1024][1024] bf16
    unsigned short* Qsc = (unsigned short*)(ws + 16777216);         // [32][2048][64] bf16 (scaled)
    unsigned short* Kb  = (unsigned short*)(ws + 25165824);         // [32][2048][64] bf16
    unsigned short* Vt  = (unsigned short*)(ws + 33554432);         // [32][64][2048] bf16
    unsigned short* ctx = (unsigned short*)(ws + 41943040);         // [4096][1024] bf16

    float* out  = (float*)d_out;
    float* attn = out + 4194304;

    convert_kernel<<<8192, 256, 0, stream>>>(x, wq, wk, wv, wo, xb, wb);
    gemm_kernel<<<dim3(24, 32), 256, 0, stream>>>(xb, wb, bq, bk, bv, 0,
                                                  Qsc, Kb, Vt, nullptr);
    attn_kernel<<<4096, 256, 0, stream>>>(Qsc, Kb, Vt, attn, ctx);
    gemm_kernel<<<dim3(8, 32), 256, 0, stream>>>(ctx, wb + 3 * 1048576, bo, bo, bo, 1,
                                                 nullptr, nullptr, nullptr, out);
}